// Round 4
// baseline (279.555 us; speedup 1.0000x reference)
//
#include <hip/hip_runtime.h>
#include <cstdint>

// ---------------------------------------------------------------------------
// CTC loss pipeline (fused):
//   k_prep : W[D,V] fp32 -> Wt[V,D] bf16 transpose, zero d_out
//   k_fused: GEMM(x fp32 -> bf16 in-reg, Wt) + bias + log_softmax + label
//            gather -> pext (linear domain). Barrier-free K-loop, operands
//            loaded directly from global (B is L2-resident), 32 rows x V=1024
//            per block.
//   k_ctc  : 4-deep pipelined scaled linear-domain CTC forward, atomic mean.
// ---------------------------------------------------------------------------

#define SPAD 260                      // padded extended-state row (257 -> 260)
#define PEXT_PAD_ROWS 64              // prefetch overrun pad (loaded, never consumed)
#define TSTRIDE 36                    // LDS logit tile: col-major, 32 rows + 4 pad (ushorts)
#define L2E 1.4426950408889634f
#define LN2 0.6931471805599453f

typedef short v8s __attribute__((ext_vector_type(8)));
typedef float v4f __attribute__((ext_vector_type(4)));

__device__ __forceinline__ uint32_t f2bf_bits(float f) {
  uint32_t u = __float_as_uint(f);
  return (u + 0x7FFFu + ((u >> 16) & 1u)) >> 16;   // RNE
}
__device__ __forceinline__ float bf2f(uint32_t h) { return __uint_as_float(h << 16); }

__device__ __forceinline__ v8s pack_bf8(float4 lo, float4 hi) {
  union { v8s v; uint16_t s[8]; } u;
  u.s[0] = (uint16_t)f2bf_bits(lo.x); u.s[1] = (uint16_t)f2bf_bits(lo.y);
  u.s[2] = (uint16_t)f2bf_bits(lo.z); u.s[3] = (uint16_t)f2bf_bits(lo.w);
  u.s[4] = (uint16_t)f2bf_bits(hi.x); u.s[5] = (uint16_t)f2bf_bits(hi.y);
  u.s[6] = (uint16_t)f2bf_bits(hi.z); u.s[7] = (uint16_t)f2bf_bits(hi.w);
  return u.v;
}

// ---------------- k_prep: W transpose -> bf16, zero d_out ----------------
__global__ void k_prep(const float* __restrict__ W, uint16_t* __restrict__ Wt, int D, int V,
                       float* __restrict__ out) {
  if (blockIdx.x == 0 && threadIdx.x == 0) out[0] = 0.f;
  __shared__ float tile[32][33];
  const int n0 = (blockIdx.x % (V / 32)) * 32, k0 = (blockIdx.x / (V / 32)) * 32;
  const int tx = threadIdx.x & 31, ty = threadIdx.x >> 5;   // (32,8)
  #pragma unroll
  for (int i = 0; i < 32; i += 8)
    tile[ty + i][tx] = W[(size_t)(k0 + ty + i) * V + n0 + tx];
  __syncthreads();
  #pragma unroll
  for (int i = 0; i < 32; i += 8)
    Wt[(size_t)(n0 + ty + i) * D + k0 + tx] = (uint16_t)f2bf_bits(tile[tx][ty + i]);
}

// ---------------- k_fused: GEMM + bias + log_softmax + gather -> pext ----------------
// Block: rows m0..m0+31 (one batch; requires T%32==0), all V cols. 4 waves,
// wave w owns cols [256w, 256w+256). No LDS, no barriers in the K-loop.
__global__ __launch_bounds__(256, 1) void k_fused(const float* __restrict__ x,
                                                  const uint16_t* __restrict__ Wt,
                                                  const float* __restrict__ bias,
                                                  const int* __restrict__ target,
                                                  const int* __restrict__ tlen,
                                                  float* __restrict__ pext,
                                                  int T, int V, int K, int L) {
  const int tid = threadIdx.x, lane = tid & 63, wave = tid >> 6;
  const int q = lane >> 4, c = lane & 15;
  const int m0 = blockIdx.x * 32;
  const int nw = wave * 256;

  v4f acc[2][16] = {};

  const float* xa0 = x + (size_t)(m0 + c) * K + q * 8;        // A-frag i=0
  const float* xa1 = x + (size_t)(m0 + 16 + c) * K + q * 8;   // A-frag i=1

  for (int k0 = 0; k0 < K; k0 += 32) {
    const v8s af0 = pack_bf8(*(const float4*)(xa0 + k0), *(const float4*)(xa0 + k0 + 4));
    const v8s af1 = pack_bf8(*(const float4*)(xa1 + k0), *(const float4*)(xa1 + k0 + 4));
    #pragma unroll
    for (int jj = 0; jj < 16; jj++) {
      const v8s bf = *(const v8s*)(Wt + (size_t)(nw + jj * 16 + c) * K + k0 + q * 8);
      acc[0][jj] = __builtin_amdgcn_mfma_f32_16x16x32_bf16(af0, bf, acc[0][jj], 0, 0, 0);
      acc[1][jj] = __builtin_amdgcn_mfma_f32_16x16x32_bf16(af1, bf, acc[1][jj], 0, 0, 0);
    }
  }

  // bias add. C/D layout: col = c (lane&15), row = 4q + r  [m89-verified]
  float bv[16];
  #pragma unroll
  for (int jj = 0; jj < 16; jj++) bv[jj] = bias[nw + jj * 16 + c];
  #pragma unroll
  for (int i = 0; i < 2; i++)
    #pragma unroll
    for (int jj = 0; jj < 16; jj++)
      #pragma unroll
      for (int r = 0; r < 4; r++) acc[i][jj][r] += bv[jj];

  // per-wave row max and exp-sum (row's cols live in this 16-lane group)
  float mx[2][4], sm[2][4];
  #pragma unroll
  for (int i = 0; i < 2; i++)
    #pragma unroll
    for (int r = 0; r < 4; r++) {
      float m = -INFINITY;
      #pragma unroll
      for (int jj = 0; jj < 16; jj++) m = fmaxf(m, acc[i][jj][r]);
      #pragma unroll
      for (int off = 1; off < 16; off <<= 1) m = fmaxf(m, __shfl_xor(m, off, 64));
      float s = 0.f;
      #pragma unroll
      for (int jj = 0; jj < 16; jj++) s += exp2f((acc[i][jj][r] - m) * L2E);
      #pragma unroll
      for (int off = 1; off < 16; off <<= 1) s += __shfl_xor(s, off, 64);
      mx[i][r] = m; sm[i][r] = s;
    }

  // LDS: bf16 logit tile (col-major) + cross-wave softmax reduce + lse
  __shared__ uint16_t ltile[1024 * TSTRIDE];   // 72 KB
  __shared__ float red_mx[4][32], red_sm[4][32], lse2s[32];

  #pragma unroll
  for (int i = 0; i < 2; i++)
    #pragma unroll
    for (int jj = 0; jj < 16; jj++) {
      union { uint16_t s[4]; uint64_t u; } pk;
      #pragma unroll
      for (int r = 0; r < 4; r++) pk.s[r] = (uint16_t)f2bf_bits(acc[i][jj][r]);
      *(uint64_t*)(ltile + (size_t)(nw + jj * 16 + c) * TSTRIDE + i * 16 + 4 * q) = pk.u;
    }
  if (c == 0) {
    #pragma unroll
    for (int i = 0; i < 2; i++)
      #pragma unroll
      for (int r = 0; r < 4; r++) {
        red_mx[wave][16 * i + 4 * q + r] = mx[i][r];
        red_sm[wave][16 * i + 4 * q + r] = sm[i][r];
      }
  }
  __syncthreads();
  if (tid < 32) {
    float M = fmaxf(fmaxf(red_mx[0][tid], red_mx[1][tid]), fmaxf(red_mx[2][tid], red_mx[3][tid]));
    float S = 0.f;
    #pragma unroll
    for (int w = 0; w < 4; w++) S += red_sm[w][tid] * exp2f((red_mx[w][tid] - M) * L2E);
    lse2s[tid] = M * L2E + log2f(S);
  }
  __syncthreads();

  // gather ext-label probs (linear domain) and write pext
  const int b = m0 / T;
  const int Lb = tlen[b];
  const int S = 2 * Lb + 1;
  const int* tg = target + b * L;
  #pragma unroll
  for (int rr = 0; rr < 8; rr++) {
    const int row = wave * 8 + rr;
    const float l2 = lse2s[row];
    float* prow = pext + (size_t)(m0 + row) * SPAD;
    for (int s = lane; s < SPAD; s += 64) {
      float p = 0.f;
      if (s < S) {
        const int lbl = (s & 1) ? tg[(s - 1) >> 1] : 0;
        p = exp2f(bf2f(ltile[(size_t)lbl * TSTRIDE + row]) * L2E - l2);
      }
      prow[s] = p;
    }
  }
}

// ---------------- k_ctc: scaled linear-domain CTC forward, 1 wave per batch ----------------
__device__ __forceinline__ float wave_shr1(float x) {   // lane l <- lane l-1, lane0 <- 0
  return __int_as_float(__builtin_amdgcn_update_dpp(0, __float_as_int(x), 0x138, 0xf, 0xf, true));
}
__device__ __forceinline__ float wave_max_nonneg(float x) {
  x = fmaxf(x, __int_as_float(__builtin_amdgcn_update_dpp(0, __float_as_int(x), 0x111, 0xf, 0xf, true)));
  x = fmaxf(x, __int_as_float(__builtin_amdgcn_update_dpp(0, __float_as_int(x), 0x112, 0xf, 0xf, true)));
  x = fmaxf(x, __int_as_float(__builtin_amdgcn_update_dpp(0, __float_as_int(x), 0x114, 0xf, 0xf, true)));
  x = fmaxf(x, __int_as_float(__builtin_amdgcn_update_dpp(0, __float_as_int(x), 0x118, 0xf, 0xf, true)));
  x = fmaxf(x, __int_as_float(__builtin_amdgcn_update_dpp(0, __float_as_int(x), 0x142, 0xf, 0xf, true)));
  x = fmaxf(x, __int_as_float(__builtin_amdgcn_update_dpp(0, __float_as_int(x), 0x143, 0xf, 0xf, true)));
  return __int_as_float(__builtin_amdgcn_readlane(__float_as_int(x), 63));
}

__device__ __forceinline__ void load8(float4* __restrict__ p, float* __restrict__ p4,
                                      const float* __restrict__ pb, int t0, int lane) {
  #pragma unroll
  for (int k = 0; k < 8; k++) {
    const float* row = pb + (size_t)(t0 + k) * SPAD;
    p[k] = *(const float4*)(row + (lane << 2));
    p4[k] = row[256];               // wave-broadcast load
  }
}

__global__ __launch_bounds__(64, 1) void k_ctc(const float* __restrict__ pext,
                                               const int* __restrict__ target,
                                               const int* __restrict__ ilen,
                                               const int* __restrict__ tlen,
                                               float* __restrict__ out, int T, int L) {
  const int b = blockIdx.x;
  const int lane = threadIdx.x;          // 64 threads = 1 wave
  const int B = gridDim.x;
  const int Tb = ilen[b];
  const int Lb = tlen[b];
  const int S = 2 * Lb + 1;
  const int* tg = target + b * L;

  const int s1 = 4 * lane + 1, s3 = 4 * lane + 3;
  float sk1 = 0.f, sk3 = 0.f;
  if (s1 >= 3 && s1 < S) sk1 = (tg[(s1 - 1) >> 1] != tg[(s1 - 3) >> 1]) ? 1.f : 0.f;
  if (s3 >= 3 && s3 < S) sk3 = (tg[(s3 - 1) >> 1] != tg[(s3 - 3) >> 1]) ? 1.f : 0.f;

  const float* pb = pext + (size_t)b * T * SPAD;
  const float4 p0 = *(const float4*)(pb + (lane << 2));
  float a0 = (lane == 0) ? p0.x : 0.f;
  float a1 = (lane == 0) ? p0.y : 0.f;
  float a2 = 0.f, a3 = 0.f, a4 = 0.f;
  float log2C = 0.f;

  #define CTC_STEP(PP, P4) {                                            \
    const float pm3 = wave_shr1(a3);                                    \
    const float a255 = __int_as_float(__builtin_amdgcn_readlane(__float_as_int(a3), 63)); \
    const float n0v = (a0 + pm3) * (PP).x;                              \
    const float n1v = (a1 + a0 + sk1 * pm3) * (PP).y;                   \
    const float n2v = (a2 + a1) * (PP).z;                               \
    const float n3v = (a3 + a2 + sk3 * a1) * (PP).w;                    \
    const float n4v = (a4 + a255) * (P4);                               \
    a0 = n0v; a1 = n1v; a2 = n2v; a3 = n3v; a4 = n4v; }

  #define RENORM {                                                      \
    float m = fmaxf(fmaxf(fmaxf(a0, a1), fmaxf(a2, a3)), a4);           \
    m = wave_max_nonneg(m);                                             \
    const int e = (int)((__float_as_uint(m) >> 23) & 255u) - 127;       \
    const float scale = __uint_as_float((uint32_t)(127 - e) << 23);     \
    a0 *= scale; a1 *= scale; a2 *= scale; a3 *= scale; a4 *= scale;    \
    log2C += (float)e; }

  float4 Pa[8], Pb_[8], Pc[8], Pd[8];
  float Qa[8], Qb[8], Qc[8], Qd[8];
  int t0 = 1;
  bool done = false;
  load8(Pa, Qa, pb, t0, lane);
  load8(Pb_, Qb, pb, t0 + 8, lane);
  load8(Pc, Qc, pb, t0 + 16, lane);

  #define PHASE(LP, LQ, CP, CQ) {                                       \
    if (t0 + 8 <= Tb) {                                                 \
      load8(LP, LQ, pb, t0 + 24, lane);                                 \
      _Pragma("unroll")                                                 \
      for (int k = 0; k < 8; k++) CTC_STEP(CP[k], CQ[k]);               \
      RENORM; t0 += 8;                                                  \
    } else {                                                            \
      _Pragma("unroll")                                                 \
      for (int k = 0; k < 8; k++) { if (t0 + k < Tb) CTC_STEP(CP[k], CQ[k]); } \
      RENORM; done = true;                                              \
    } }

  while (!done) {
    PHASE(Pd, Qd, Pa, Qa); if (done) break;
    PHASE(Pa, Qa, Pb_, Qb); if (done) break;
    PHASE(Pb_, Qb, Pc, Qc); if (done) break;
    PHASE(Pc, Qc, Pd, Qd);
  }

  __shared__ float abuf[257];
  abuf[4 * lane + 0] = a0; abuf[4 * lane + 1] = a1;
  abuf[4 * lane + 2] = a2; abuf[4 * lane + 3] = a3;
  if (lane == 63) abuf[256] = a4;
  __syncthreads();
  if (lane == 0) {
    const float ssum = abuf[2 * Lb - 1] + abuf[2 * Lb];
    const float ll = (log2f(ssum) + log2C) * LN2;
    float nll = -ll;
    if (!(nll < 1e29f)) nll = 0.f;                 // zero_infinity (also catches inf/nan)
    atomicAdd(out, nll / ((float)(Lb > 0 ? Lb : 1) * (float)B));
  }
}

// ---------------------------------------------------------------------------
extern "C" void kernel_launch(void* const* d_in, const int* in_sizes, int n_in,
                              void* d_out, int out_size, void* d_ws, size_t ws_size,
                              hipStream_t stream) {
  const float* x      = (const float*)d_in[0];
  const float* W      = (const float*)d_in[1];
  const float* bias   = (const float*)d_in[2];
  const int*  target  = (const int*)d_in[3];
  const int*  ilen    = (const int*)d_in[4];
  const int*  tlen    = (const int*)d_in[5];

  const int B = in_sizes[4];
  const int V = in_sizes[2];
  const int D = in_sizes[1] / V;
  const int T = in_sizes[0] / (B * D);
  const int L = in_sizes[3] / B;
  const int M = B * T;

  char* ws = (char*)d_ws;
  const size_t wt_bytes = (size_t)V * D * 2;
  uint16_t* Wt = (uint16_t*)ws;
  float* pext = (float*)(ws + wt_bytes);

  k_prep<<<(V / 32) * (D / 32), 256, 0, stream>>>(W, Wt, D, V, (float*)d_out);
  k_fused<<<M / 32, 256, 0, stream>>>(x, Wt, bias, target, tlen, pext, T, V, D, L);
  k_ctc<<<B, 64, 0, stream>>>(pext, target, ilen, tlen, (float*)d_out, T, L);
}

// Round 5
// 168.369 us; speedup vs baseline: 1.6604x; 1.6604x over previous
//
#include <hip/hip_runtime.h>
#include <cstdint>

// ---------------------------------------------------------------------------
// CTC loss pipeline:
//   k_prep : x fp32->bf16, W[D,V] -> Wt[V,D] bf16, zero d_out
//   k_gemm : m97-structure bf16 MFMA GEMM, BK=64 (2 K-halves per barrier pair)
//   k_softmax_gather : row lse + ext-label exp-gather -> pext (linear domain)
//   k_ctc  : 4-deep pipelined scaled linear-domain CTC forward (sched_barrier
//            forces batched prefetch), atomic mean into d_out.
// ---------------------------------------------------------------------------

#define SPAD 260                      // padded extended-state row (257 -> 260)
#define PEXT_PAD_ROWS 64              // prefetch overrun pad (loaded, never consumed)
#define L2E 1.4426950408889634f
#define LN2 0.6931471805599453f

typedef short v8s __attribute__((ext_vector_type(8)));
typedef float v4f __attribute__((ext_vector_type(4)));

__device__ __forceinline__ uint32_t f2bf_bits(float f) {
  uint32_t u = __float_as_uint(f);
  return (u + 0x7FFFu + ((u >> 16) & 1u)) >> 16;   // RNE
}
__device__ __forceinline__ float bf2f(uint32_t h) { return __uint_as_float(h << 16); }

// ---------------- k_prep: x fp32->bf16, W transpose->bf16, zero d_out ----------------
__global__ void k_prep(const float* __restrict__ x, uint16_t* __restrict__ xb, long long n,
                       const float* __restrict__ W, uint16_t* __restrict__ Wt, int D, int V,
                       float* __restrict__ out, int nconv) {
  if (blockIdx.x == 0 && threadIdx.x == 0) out[0] = 0.f;   // zero the atomic target
  if ((int)blockIdx.x < nconv) {
    long long i = ((long long)blockIdx.x * blockDim.x + threadIdx.x) * 8;
    if (i >= n) return;
    float4 a = *(const float4*)(x + i);
    float4 b = *(const float4*)(x + i + 4);
    uint4 o;
    o.x = f2bf_bits(a.x) | (f2bf_bits(a.y) << 16);
    o.y = f2bf_bits(a.z) | (f2bf_bits(a.w) << 16);
    o.z = f2bf_bits(b.x) | (f2bf_bits(b.y) << 16);
    o.w = f2bf_bits(b.z) | (f2bf_bits(b.w) << 16);
    *(uint4*)(xb + i) = o;
  } else {
    __shared__ float tile[32][33];
    const int bid2 = blockIdx.x - nconv;
    const int n0 = (bid2 % (V / 32)) * 32, k0 = (bid2 / (V / 32)) * 32;
    const int tx = threadIdx.x & 31, ty = threadIdx.x >> 5;   // (32,8)
    #pragma unroll
    for (int i = 0; i < 32; i += 8)
      tile[ty + i][tx] = W[(size_t)(k0 + ty + i) * V + n0 + tx];
    __syncthreads();
    #pragma unroll
    for (int i = 0; i < 32; i += 8)
      Wt[(size_t)(n0 + ty + i) * D + k0 + tx] = (uint16_t)f2bf_bits(tile[tx][ty + i]);
  }
}

// ---------------- k_gemm: m97 structure, BK=64, bf16 out ----------------
// A:[M,K] bf16, Bt:[N,K] bf16 (=W^T). 128x128 tile, 4 waves, 2 K-halves per
// barrier pair (32 MFMA/barrier). LDS 32 KB.
__global__ __launch_bounds__(256) void k_gemm(const uint16_t* __restrict__ A,
                                              const uint16_t* __restrict__ Bt,
                                              const float* __restrict__ bias,
                                              uint16_t* __restrict__ C, int M, int N, int K) {
  __shared__ uint16_t As[2][128 * 32];   // [k-half][row*32 + k]  (64B rows)
  __shared__ uint16_t Bs[2][128 * 32];
  const int tid = threadIdx.x, lane = tid & 63, wave = tid >> 6;
  const int m0 = blockIdx.x * 128, n0 = blockIdx.y * 128;
  const int wm = wave & 1, wn = wave >> 1;
  const int frow = lane & 15, kb = lane >> 4;
  const int lr = lane >> 2, kc = lane & 3;
  v4f acc[4][4] = {};

  for (int k0 = 0; k0 < K; k0 += 64) {
    __syncthreads();
    #pragma unroll
    for (int t = 0; t < 2; t++)
      #pragma unroll
      for (int i = 0; i < 2; i++) {
        const int r = (wave * 2 + i) * 16 + lr;
        const uint16_t* ga = A + (size_t)(m0 + r) * K + k0 + t * 32 + kc * 8;
        const uint16_t* gb = Bt + (size_t)(n0 + r) * K + k0 + t * 32 + kc * 8;
        __builtin_amdgcn_global_load_lds(
            (const __attribute__((address_space(1))) void*)ga,
            (__attribute__((address_space(3))) void*)(&As[t][0] + (wave * 2 + i) * 512 + lane * 8), 16, 0, 0);
        __builtin_amdgcn_global_load_lds(
            (const __attribute__((address_space(1))) void*)gb,
            (__attribute__((address_space(3))) void*)(&Bs[t][0] + (wave * 2 + i) * 512 + lane * 8), 16, 0, 0);
      }
    __syncthreads();

    #pragma unroll
    for (int t = 0; t < 2; t++) {
      v8s af[4], bf[4];
      #pragma unroll
      for (int i = 0; i < 4; i++)
        af[i] = *(const v8s*)(&As[t][0] + (wm * 64 + i * 16 + frow) * 32 + kb * 8);
      #pragma unroll
      for (int j = 0; j < 4; j++)
        bf[j] = *(const v8s*)(&Bs[t][0] + (wn * 64 + j * 16 + frow) * 32 + kb * 8);
      #pragma unroll
      for (int i = 0; i < 4; i++)
        #pragma unroll
        for (int j = 0; j < 4; j++)
          acc[i][j] = __builtin_amdgcn_mfma_f32_16x16x32_bf16(af[i], bf[j], acc[i][j], 0, 0, 0);
    }
  }

  // epilogue: C/D layout col=lane&15, row=(lane>>4)*4+reg  [m89-verified]
  const int crow = (lane >> 4) * 4, ccol = lane & 15;
  #pragma unroll
  for (int j = 0; j < 4; j++) {
    const int n = n0 + wn * 64 + j * 16 + ccol;
    const float bv = bias[n];
    #pragma unroll
    for (int i = 0; i < 4; i++) {
      const int mb = m0 + wm * 64 + i * 16 + crow;
      #pragma unroll
      for (int r2 = 0; r2 < 4; r2++)
        C[(size_t)(mb + r2) * N + n] = (uint16_t)f2bf_bits(acc[i][j][r2] + bv);
    }
  }
}

// ---------------- k_softmax_gather: row lse + gather (linear domain) ----------------
__global__ void k_softmax_gather(const uint16_t* __restrict__ logits, const int* __restrict__ target,
                                 const int* __restrict__ tlen, float* __restrict__ pext,
                                 int T, int V, int L) {
  const int row = blockIdx.x * 4 + (threadIdx.x >> 6);   // one wave per row
  const int lane = threadIdx.x & 63;
  const uint16_t* lrow = logits + (size_t)row * V;

  float xs[16];
  int cnt = 0;
  float mx = -INFINITY;
  for (int base = 0; base < V; base += 256) {
    const int idx = base + lane * 4;
    uint2 u = *(const uint2*)(lrow + idx);
    float4 v;
    v.x = bf2f(u.x & 0xFFFFu); v.y = bf2f(u.x >> 16);
    v.z = bf2f(u.y & 0xFFFFu); v.w = bf2f(u.y >> 16);
    xs[cnt] = v.x; xs[cnt + 1] = v.y; xs[cnt + 2] = v.z; xs[cnt + 3] = v.w; cnt += 4;
    mx = fmaxf(mx, fmaxf(fmaxf(v.x, v.y), fmaxf(v.z, v.w)));
  }
  #pragma unroll
  for (int off = 32; off; off >>= 1) mx = fmaxf(mx, __shfl_xor(mx, off, 64));
  float sum = 0.f;
  #pragma unroll
  for (int q = 0; q < 16; q++) { if (q < cnt) sum += exp2f((xs[q] - mx) * L2E); }
  #pragma unroll
  for (int off = 32; off; off >>= 1) sum += __shfl_xor(sum, off, 64);
  const float lse2 = mx * L2E + log2f(sum);

  const int bidx = row / T;
  const int Lb = tlen[bidx];
  const int S = 2 * Lb + 1;
  float* prow = pext + (size_t)row * SPAD;
  for (int s = lane; s < SPAD; s += 64) {
    float p = 0.f;
    if (s < S) {
      const int lbl = (s & 1) ? target[bidx * L + ((s - 1) >> 1)] : 0;
      p = exp2f(bf2f(lrow[lbl]) * L2E - lse2);
    }
    prow[s] = p;
  }
}

// ---------------- k_ctc: scaled linear-domain CTC forward, 1 wave per batch ----------------
__device__ __forceinline__ float wave_shr1(float x) {   // lane l <- lane l-1, lane0 <- 0
  return __int_as_float(__builtin_amdgcn_update_dpp(0, __float_as_int(x), 0x138, 0xf, 0xf, true));
}
__device__ __forceinline__ float wave_max_nonneg(float x) {
  x = fmaxf(x, __int_as_float(__builtin_amdgcn_update_dpp(0, __float_as_int(x), 0x111, 0xf, 0xf, true)));
  x = fmaxf(x, __int_as_float(__builtin_amdgcn_update_dpp(0, __float_as_int(x), 0x112, 0xf, 0xf, true)));
  x = fmaxf(x, __int_as_float(__builtin_amdgcn_update_dpp(0, __float_as_int(x), 0x114, 0xf, 0xf, true)));
  x = fmaxf(x, __int_as_float(__builtin_amdgcn_update_dpp(0, __float_as_int(x), 0x118, 0xf, 0xf, true)));
  x = fmaxf(x, __int_as_float(__builtin_amdgcn_update_dpp(0, __float_as_int(x), 0x142, 0xf, 0xf, true)));
  x = fmaxf(x, __int_as_float(__builtin_amdgcn_update_dpp(0, __float_as_int(x), 0x143, 0xf, 0xf, true)));
  return __int_as_float(__builtin_amdgcn_readlane(__float_as_int(x), 63));
}

// 8-row chunk load: pure loads — no clamps, no selects, no guards.
__device__ __forceinline__ void load8(float4* __restrict__ p, float* __restrict__ p4,
                                      const float* __restrict__ pb, int t0, int lane) {
  #pragma unroll
  for (int k = 0; k < 8; k++) {
    const float* row = pb + (size_t)(t0 + k) * SPAD;
    p[k] = *(const float4*)(row + (lane << 2));
    p4[k] = row[256];               // wave-broadcast load
  }
}

__global__ __launch_bounds__(64, 1) void k_ctc(const float* __restrict__ pext,
                                               const int* __restrict__ target,
                                               const int* __restrict__ ilen,
                                               const int* __restrict__ tlen,
                                               float* __restrict__ out, int T, int L) {
  const int b = blockIdx.x;
  const int lane = threadIdx.x;          // 64 threads = 1 wave
  const int B = gridDim.x;
  const int Tb = ilen[b];
  const int Lb = tlen[b];
  const int S = 2 * Lb + 1;
  const int* tg = target + b * L;

  const int s1 = 4 * lane + 1, s3 = 4 * lane + 3;
  float sk1 = 0.f, sk3 = 0.f;
  if (s1 >= 3 && s1 < S) sk1 = (tg[(s1 - 1) >> 1] != tg[(s1 - 3) >> 1]) ? 1.f : 0.f;
  if (s3 >= 3 && s3 < S) sk3 = (tg[(s3 - 1) >> 1] != tg[(s3 - 3) >> 1]) ? 1.f : 0.f;

  const float* pb = pext + (size_t)b * T * SPAD;
  const float4 p0 = *(const float4*)(pb + (lane << 2));
  float a0 = (lane == 0) ? p0.x : 0.f;
  float a1 = (lane == 0) ? p0.y : 0.f;
  float a2 = 0.f, a3 = 0.f, a4 = 0.f;
  float log2C = 0.f;

  #define CTC_STEP(PP, P4) {                                            \
    const float pm3 = wave_shr1(a3);                                    \
    const float a255 = __int_as_float(__builtin_amdgcn_readlane(__float_as_int(a3), 63)); \
    const float n0v = (a0 + pm3) * (PP).x;                              \
    const float n1v = (a1 + a0 + sk1 * pm3) * (PP).y;                   \
    const float n2v = (a2 + a1) * (PP).z;                               \
    const float n3v = (a3 + a2 + sk3 * a1) * (PP).w;                    \
    const float n4v = (a4 + a255) * (P4);                               \
    a0 = n0v; a1 = n1v; a2 = n2v; a3 = n3v; a4 = n4v; }

  #define RENORM {                                                      \
    float m = fmaxf(fmaxf(fmaxf(a0, a1), fmaxf(a2, a3)), a4);           \
    m = wave_max_nonneg(m);                                             \
    const int e = (int)((__float_as_uint(m) >> 23) & 255u) - 127;       \
    const float scale = __uint_as_float((uint32_t)(127 - e) << 23);     \
    a0 *= scale; a1 *= scale; a2 *= scale; a3 *= scale; a4 *= scale;    \
    log2C += (float)e; }

  // 4-stage software pipeline, 8-row chunks, prefetch distance = 3 chunks.
  // sched_barrier(0) after each load block pins the loads ABOVE the compute:
  // without it the compiler sinks each load to its first use (R1 evidence:
  // VGPR_Count=64 with two 16-row "buffers"), serializing on memory latency.
  float4 Pa[8], Pb_[8], Pc[8], Pd[8];
  float Qa[8], Qb[8], Qc[8], Qd[8];
  int t0 = 1;
  bool done = false;
  load8(Pa, Qa, pb, t0, lane);
  load8(Pb_, Qb, pb, t0 + 8, lane);
  load8(Pc, Qc, pb, t0 + 16, lane);
  __builtin_amdgcn_sched_barrier(0);

  #define PHASE(LP, LQ, CP, CQ) {                                       \
    if (t0 + 8 <= Tb) {                                                 \
      load8(LP, LQ, pb, t0 + 24, lane);                                 \
      __builtin_amdgcn_sched_barrier(0);                                \
      _Pragma("unroll")                                                 \
      for (int k = 0; k < 8; k++) CTC_STEP(CP[k], CQ[k]);               \
      RENORM; t0 += 8;                                                  \
    } else {                                                            \
      _Pragma("unroll")                                                 \
      for (int k = 0; k < 8; k++) { if (t0 + k < Tb) CTC_STEP(CP[k], CQ[k]); } \
      RENORM; done = true;                                              \
    } }

  while (!done) {
    PHASE(Pd, Qd, Pa, Qa); if (done) break;
    PHASE(Pa, Qa, Pb_, Qb); if (done) break;
    PHASE(Pb_, Qb, Pc, Qc); if (done) break;
    PHASE(Pc, Qc, Pd, Qd);
  }

  __shared__ float abuf[257];
  abuf[4 * lane + 0] = a0; abuf[4 * lane + 1] = a1;
  abuf[4 * lane + 2] = a2; abuf[4 * lane + 3] = a3;
  if (lane == 63) abuf[256] = a4;
  __syncthreads();
  if (lane == 0) {
    const float ssum = abuf[2 * Lb - 1] + abuf[2 * Lb];
    const float ll = (log2f(ssum) + log2C) * LN2;
    float nll = -ll;
    if (!(nll < 1e29f)) nll = 0.f;                 // zero_infinity (also catches inf/nan)
    atomicAdd(out, nll / ((float)(Lb > 0 ? Lb : 1) * (float)B));
  }
}

// ---------------------------------------------------------------------------
extern "C" void kernel_launch(void* const* d_in, const int* in_sizes, int n_in,
                              void* d_out, int out_size, void* d_ws, size_t ws_size,
                              hipStream_t stream) {
  const float* x      = (const float*)d_in[0];
  const float* W      = (const float*)d_in[1];
  const float* bias   = (const float*)d_in[2];
  const int*  target  = (const int*)d_in[3];
  const int*  ilen    = (const int*)d_in[4];
  const int*  tlen    = (const int*)d_in[5];

  const int B = in_sizes[4];
  const int V = in_sizes[2];
  const int D = in_sizes[1] / V;
  const int T = in_sizes[0] / (B * D);
  const int L = in_sizes[3] / B;
  const int M = B * T;

  char* ws = (char*)d_ws;
  const size_t xb_bytes = (size_t)M * D * 2;
  const size_t wt_bytes = (size_t)V * D * 2;
  const size_t pext_bytes = (size_t)(M + PEXT_PAD_ROWS) * SPAD * 4;
  uint16_t* xb = (uint16_t*)ws;
  uint16_t* Wt = (uint16_t*)(ws + xb_bytes);
  uint16_t* logits = (uint16_t*)(ws + xb_bytes + wt_bytes);
  const size_t log_bytes = (size_t)M * V * 2;

  float* pext;
  if (pext_bytes <= xb_bytes + wt_bytes) {
    pext = (float*)ws;                 // overlay dead xb/Wt region after GEMM
  } else {
    pext = (float*)(ws + xb_bytes + wt_bytes + log_bytes);
  }

  const long long nx = (long long)M * D;
  const int nconv = (int)((nx / 8 + 255) / 256);
  const int ntrans = (V / 32) * (D / 32);
  k_prep<<<nconv + ntrans, 256, 0, stream>>>(x, xb, nx, W, Wt, D, V, (float*)d_out, nconv);
  k_gemm<<<dim3(M / 128, V / 128), 256, 0, stream>>>(xb, Wt, bias, logits, M, V, D);
  k_softmax_gather<<<M / 4, 256, 0, stream>>>(logits, target, tlen, pext, T, V, L);
  k_ctc<<<B, 64, 0, stream>>>(pext, target, ilen, tlen, (float*)d_out, T, L);
}